// Round 10
// baseline (1396.144 us; speedup 1.0000x reference)
//
#include <hip/hip_runtime.h>
#include <type_traits>

// LSTMNet: B=1024, T=2048, H=64, NC=10, input_size=1.
// MFMA (16x16x32 bf16) split-bf16 (hi+lo) fp32 emulation.
// R10: wave specialization + conflict-free LDS layouts.
//   grid = 128 blocks x 512 thr (8 waves); block owns 8 batch rows.
//   Waves 0-3 (compute): wave g owns gate g, all 4 unit-16-tiles ->
//     24 MFMAs/wave; writes gates to gbuf[m][g][u] (unit-stride -> 2-way free).
//   Waves 4-7 (update): 2 cells/lane (rows 2uw,2uw+1, unit=lane); 1 barrier
//     later writes h hi/lo into SWIZZLED A-frag rows: phys(R) = R*8+(R>>4)*8
//     shorts (16B-preserving) -> writer hits all 32 banks (R9: 4 banks,
//     16-way, 76M conflict cycles).
//   A-frag reads: only 4 compute waves x 4 b128 = 16/step (R9: 32).
// R9 post-mortem: LDS pipe was ~900 of 1470 cyc/step (duplicated A reads +
// 4-way gbuf + 16-way h-scatter). This cuts it to ~350.

#define T_STEPS 2048
#define HID 64
#define NCLS 10
#define XCH 128   // x chunk length (steps)
#define ROWS 8    // batch rows per block

typedef short bf16x8 __attribute__((ext_vector_type(8)));
typedef float f32x4 __attribute__((ext_vector_type(4)));

__device__ __forceinline__ float sigm(float x) {
    float e = __builtin_amdgcn_exp2f(-1.4426950408889634f * x);
    return __builtin_amdgcn_rcpf(1.0f + e);
}
__device__ __forceinline__ float tanh_f(float x) {
    float e = __builtin_amdgcn_exp2f(-2.8853900817779268f * x);
    return fmaf(2.0f, __builtin_amdgcn_rcpf(1.0f + e), -1.0f);
}
__device__ __forceinline__ unsigned short f2bf(float f) {  // RNE f32->bf16
    unsigned u = __builtin_bit_cast(unsigned, f);
    u = u + 0x7FFFu + ((u >> 16) & 1u);
    return (unsigned short)(u >> 16);
}
__device__ __forceinline__ float bf2f(unsigned short s) {
    return __builtin_bit_cast(float, ((unsigned)s) << 16);
}

__global__ __attribute__((amdgpu_flat_work_group_size(512, 512),
                          amdgpu_waves_per_eu(2, 2)))
void lstm_mfma_kernel(
    const float* __restrict__ x,      // [B, 1, T]
    const float* __restrict__ W_ih,   // [256, 1]
    const float* __restrict__ W_hh,   // [256, 64]
    const float* __restrict__ b_ih,   // [256]
    const float* __restrict__ b_hh,   // [256]
    const float* __restrict__ fc1_w,  // [64, 64]
    const float* __restrict__ fc1_b,  // [64]
    const float* __restrict__ fc2_w,  // [10, 64]
    const float* __restrict__ fc2_b,  // [10]
    float* __restrict__ out)          // [B, 10]
{
    const int tid  = threadIdx.x;
    const int lane = tid & 63;
    const int w    = tid >> 6;        // wave id: 0-3 compute, 4-7 update
    const int quad = lane >> 4;
    const int col  = lane & 15;
    const int row0 = blockIdx.x * ROWS;

    __shared__ short whi[32 * 512];          // 32 KB: W_hh hi fragments
    __shared__ short wlo[32 * 512];          // 32 KB: W_hh lo fragments
    // A-frag double buffer: per buffer, hi rows at swizzled offsets [0,1088),
    // lo at [1088,2176). phys(R) = R*8 + (R>>4)*8 shorts, R in [0,128).
    __shared__ short abuf[2][2176];
    __shared__ float gbuf[ROWS][4][HID];     // 8 KB: gates [m][g][u], u-stride 1
    __shared__ __align__(16) float xlds[ROWS][XCH + 4];
    __shared__ float hf[ROWS][HID + 1];
    __shared__ float r1buf[ROWS][HID + 1];

    // ---- setup: W_hh f32 -> bf16 hi/lo fragments in LDS (R5-verified layout)
    for (int idx = tid; idx < 256 * 64; idx += 512) {
        int r_ = idx >> 6;            // gate-major row 0..255
        int k  = idx & 63;
        float f = W_hh[r_ * 64 + k];
        unsigned short hi = f2bf(f);
        unsigned short lo = f2bf(f - bf2f(hi));
        int g = r_ >> 6, u = r_ & 63;
        int u4 = u >> 4, n = u & 15;
        int kt = k >> 5, kq = (k & 31) >> 3, j = k & 7;
        int off = (((u4 * 4 + g) * 2 + kt) * 64 + (kq * 16 + n)) * 8 + j;
        whi[off] = (short)hi;
        wlo[off] = (short)lo;
    }
    // zero BOTH A buffers (incl. never-written rows 8..15 -> stay zero)
    for (int idx = tid; idx < 2 * 2176; idx += 512) ((short*)abuf)[idx] = 0;
    __syncthreads();

    // ---- compute-wave constants (w<4): gate g = w, all 4 unit tiles ----
    bf16x8 Bhi[4][2], Blo[4][2];
    f32x4 biasC[4];
    f32x4 zerov = {0.f, 0.f, 0.f, 0.f};
    if (w < 4) {
        const int g = w;
        #pragma unroll
        for (int tt = 0; tt < 4; ++tt) {
            int t_ = tt * 4 + g;
            #pragma unroll
            for (int kt = 0; kt < 2; ++kt) {
                int off = ((t_ * 2 + kt) * 64 + lane) * 8;
                Bhi[tt][kt] = *(const bf16x8*)&whi[off];
                Blo[tt][kt] = *(const bf16x8*)&wlo[off];
                asm volatile("" : "+v"(Bhi[tt][kt]));
                asm volatile("" : "+v"(Blo[tt][kt]));
            }
            int u = tt * 16 + col;
            float bs = b_ih[g * HID + u] + b_hh[g * HID + u];
            #pragma unroll
            for (int r = 0; r < 4; ++r) biasC[tt][r] = bs;
        }
    }

    // ---- update-wave constants (w>=4): rows m0=2uw, m1=2uw+1; unit=lane ----
    float wih_u[4];
    int m0 = 0, m1 = 0, awr0 = 0;
    float c0 = 0.f, c1 = 0.f, h0l = 0.f, h1l = 0.f;
    if (w >= 4) {
        int uw = w - 4;
        m0 = uw * 2; m1 = m0 + 1;
        #pragma unroll
        for (int g = 0; g < 4; ++g) wih_u[g] = W_ih[g * HID + lane];
        // A-frag row for cell (m, k=lane): R = (lane>>5)*64+((lane>>3)&3)*16+m
        int s = (lane >> 5) * 4 + ((lane >> 3) & 3);   // = R>>4 (m<16)
        int R0 = s * 16 + m0;
        awr0 = R0 * 8 + s * 8 + (lane & 7);            // swizzled; m1 at +8
    }

    // compute-wave A-read offsets (swizzle folded in; kt=1 at +544)
    const int ard0 = lane * 8 + (lane >> 4) * 8;

    const float* xbase = x + (size_t)row0 * T_STEPS;

    auto step = [&](auto cur_c, int tl) __attribute__((always_inline)) {
        constexpr int CUR = decltype(cur_c)::value;
        constexpr int NXT = CUR ^ 1;

        if (w < 4) {
            // ---- compute phase: gate w over all 64 units ----
            bf16x8 Ahi0 = *(const bf16x8*)&abuf[CUR][ard0];
            bf16x8 Ahi1 = *(const bf16x8*)&abuf[CUR][ard0 + 544];
            bf16x8 Alo0 = *(const bf16x8*)&abuf[CUR][1088 + ard0];
            bf16x8 Alo1 = *(const bf16x8*)&abuf[CUR][1088 + ard0 + 544];

            f32x4 accA[4], accB[4];
            #pragma unroll
            for (int tt = 0; tt < 4; ++tt) {
                accA[tt] = __builtin_amdgcn_mfma_f32_16x16x32_bf16(Ahi0, Bhi[tt][0], biasC[tt], 0, 0, 0);
                accB[tt] = __builtin_amdgcn_mfma_f32_16x16x32_bf16(Ahi1, Bhi[tt][1], zerov, 0, 0, 0);
            }
            #pragma unroll
            for (int tt = 0; tt < 4; ++tt) {
                accA[tt] = __builtin_amdgcn_mfma_f32_16x16x32_bf16(Alo0, Bhi[tt][0], accA[tt], 0, 0, 0);
                accB[tt] = __builtin_amdgcn_mfma_f32_16x16x32_bf16(Alo1, Bhi[tt][1], accB[tt], 0, 0, 0);
            }
            #pragma unroll
            for (int tt = 0; tt < 4; ++tt) {
                accA[tt] = __builtin_amdgcn_mfma_f32_16x16x32_bf16(Ahi0, Blo[tt][0], accA[tt], 0, 0, 0);
                accB[tt] = __builtin_amdgcn_mfma_f32_16x16x32_bf16(Ahi1, Blo[tt][1], accB[tt], 0, 0, 0);
            }

            if (quad < 2) {   // valid rows m = quad*4+r in 0..7
                #pragma unroll
                for (int tt = 0; tt < 4; ++tt) {
                    int u = tt * 16 + col;
                    #pragma unroll
                    for (int r = 0; r < 4; ++r) {
                        gbuf[quad * 4 + r][w][u] = accA[tt][r] + accB[tt][r];
                    }
                }
            }
        }
        __syncthreads();   // gates visible

        if (w >= 4) {
            // ---- update phase: 2 cells (m0,lane), (m1,lane) ----
            float xv0 = xlds[m0][tl];   // wave-uniform broadcasts
            float xv1 = xlds[m1][tl];

            float a00 = fmaf(xv0, wih_u[0], gbuf[m0][0][lane]);
            float a01 = fmaf(xv0, wih_u[1], gbuf[m0][1][lane]);
            float a02 = fmaf(xv0, wih_u[2], gbuf[m0][2][lane]);
            float a03 = fmaf(xv0, wih_u[3], gbuf[m0][3][lane]);
            float a10 = fmaf(xv1, wih_u[0], gbuf[m1][0][lane]);
            float a11 = fmaf(xv1, wih_u[1], gbuf[m1][1][lane]);
            float a12 = fmaf(xv1, wih_u[2], gbuf[m1][2][lane]);
            float a13 = fmaf(xv1, wih_u[3], gbuf[m1][3][lane]);

            float ig0 = sigm(a00), fg0 = sigm(a01), gg0 = tanh_f(a02), og0 = sigm(a03);
            float ig1 = sigm(a10), fg1 = sigm(a11), gg1 = tanh_f(a12), og1 = sigm(a13);
            c0 = fmaf(fg0, c0, ig0 * gg0);
            c1 = fmaf(fg1, c1, ig1 * gg1);
            float h0 = og0 * tanh_f(c0);
            float h1 = og1 * tanh_f(c1);
            h0l = h0; h1l = h1;

            unsigned short hh0 = f2bf(h0);
            unsigned short hl0 = f2bf(h0 - bf2f(hh0));
            unsigned short hh1 = f2bf(h1);
            unsigned short hl1 = f2bf(h1 - bf2f(hh1));

            abuf[NXT][awr0]            = (short)hh0;
            abuf[NXT][awr0 + 8]        = (short)hh1;   // m1 row = m0 row + 1
            abuf[NXT][1088 + awr0]     = (short)hl0;
            abuf[NXT][1088 + awr0 + 8] = (short)hl1;
        }
        __syncthreads();   // new h-frags visible
    };

    #pragma unroll 1
    for (int tc = 0; tc < T_STEPS; tc += 2) {
        const int tl = tc & (XCH - 1);
        if (tl == 0) {
            // refill x chunk (prev barrier => old chunk fully consumed)
            if (tid < 128) {
                int xr = tid >> 4, tb = (tid & 15) * 8;
                const float* src = xbase + (size_t)xr * T_STEPS + tc + tb;
                float4 v0 = *(const float4*)(src);
                float4 v1 = *(const float4*)(src + 4);
                *(float4*)&xlds[xr][tb]     = v0;
                *(float4*)&xlds[xr][tb + 4] = v1;
            }
            __syncthreads();
        }
        step(std::integral_constant<int, 0>{}, tl);      // reads abuf[0], writes abuf[1]
        step(std::integral_constant<int, 1>{}, tl + 1);  // reads abuf[1], writes abuf[0]
    }

    // ---- epilogue: fc1 (relu) + fc2 ----
    if (w >= 4) {
        hf[m0][lane] = h0l;
        hf[m1][lane] = h1l;
    }
    __syncthreads();

    {
        // thread -> output (row m_ = tid>>6, unit = lane)
        int m_ = tid >> 6;
        float s = fc1_b[lane];
        const float4* wrow = (const float4*)(fc1_w + lane * HID);
        #pragma unroll
        for (int j4 = 0; j4 < HID / 4; ++j4) {
            float4 wv = wrow[j4];
            s = fmaf(hf[m_][j4 * 4 + 0], wv.x, s);
            s = fmaf(hf[m_][j4 * 4 + 1], wv.y, s);
            s = fmaf(hf[m_][j4 * 4 + 2], wv.z, s);
            s = fmaf(hf[m_][j4 * 4 + 3], wv.w, s);
        }
        r1buf[m_][lane] = fmaxf(s, 0.0f);
    }
    __syncthreads();

    if (tid < ROWS * NCLS) {
        int m = tid / NCLS, cls = tid % NCLS;
        float s = fc2_b[cls];
        const float* w2 = fc2_w + cls * HID;
        #pragma unroll
        for (int j = 0; j < HID; ++j) s = fmaf(r1buf[m][j], w2[j], s);
        out[(size_t)(row0 + m) * NCLS + cls] = s;
    }
}

extern "C" void kernel_launch(void* const* d_in, const int* in_sizes, int n_in,
                              void* d_out, int out_size, void* d_ws, size_t ws_size,
                              hipStream_t stream) {
    const float* x     = (const float*)d_in[0];
    const float* W_ih  = (const float*)d_in[1];
    const float* W_hh  = (const float*)d_in[2];
    const float* b_ih  = (const float*)d_in[3];
    const float* b_hh  = (const float*)d_in[4];
    const float* fc1_w = (const float*)d_in[5];
    const float* fc1_b = (const float*)d_in[6];
    const float* fc2_w = (const float*)d_in[7];
    const float* fc2_b = (const float*)d_in[8];
    float* out = (float*)d_out;

    dim3 grid(128);   // 1024 rows / 8 rows per block
    dim3 block(512);  // 8 waves: 4 compute + 4 update
    lstm_mfma_kernel<<<grid, block, 0, stream>>>(x, W_ih, W_hh, b_ih, b_hh,
                                                 fc1_w, fc1_b, fc2_w, fc2_b, out);
}

// Round 11
// 1264.304 us; speedup vs baseline: 1.1043x; 1.1043x over previous
//
#include <hip/hip_runtime.h>
#include <type_traits>

// LSTMNet: B=1024, T=2048, H=64, NC=10, input_size=1.
// MFMA (16x16x32 bf16) split-bf16 (hi+lo) fp32 emulation.
// R11: use ALL 256 CUs. 256 blocks x 256 thr (4 waves); block owns only 4
// batch rows (M-tile 75% zero rows — affordable, MfmaUtil is ~12%).
//   Per step, every wave does BOTH phases (R10 lesson: specialization
//   serializes; R9's everyone-does-both wins):
//     compute: wave g owns gate g, all 4 unit-16-tiles -> 24 MFMAs;
//       gates -> gbuf[m][u][4] (2-way banks, free).
//     update:  wave w = row w, lane = unit -> 1 cell/thread, 10 trans/wave;
//       h hi/lo into R10-verified swizzled abuf rows (2-way banks).
//   2 barriers/step; per-CU LDS traffic and trans work HALVED vs R9.
// History: R9 (128 CUs, both-phases) 1280us; R10 (specialized) 1396us.

#define T_STEPS 2048
#define HID 64
#define NCLS 10
#define XCH 128   // x chunk length (steps)
#define ROWS 4    // batch rows per block

typedef short bf16x8 __attribute__((ext_vector_type(8)));
typedef float f32x4 __attribute__((ext_vector_type(4)));

__device__ __forceinline__ float sigm(float x) {
    float e = __builtin_amdgcn_exp2f(-1.4426950408889634f * x);
    return __builtin_amdgcn_rcpf(1.0f + e);
}
__device__ __forceinline__ float tanh_f(float x) {
    float e = __builtin_amdgcn_exp2f(-2.8853900817779268f * x);
    return fmaf(2.0f, __builtin_amdgcn_rcpf(1.0f + e), -1.0f);
}
__device__ __forceinline__ unsigned short f2bf(float f) {  // RNE f32->bf16
    unsigned u = __builtin_bit_cast(unsigned, f);
    u = u + 0x7FFFu + ((u >> 16) & 1u);
    return (unsigned short)(u >> 16);
}
__device__ __forceinline__ float bf2f(unsigned short s) {
    return __builtin_bit_cast(float, ((unsigned)s) << 16);
}

__global__ __attribute__((amdgpu_flat_work_group_size(256, 256),
                          amdgpu_waves_per_eu(1, 1)))
void lstm_mfma_kernel(
    const float* __restrict__ x,      // [B, 1, T]
    const float* __restrict__ W_ih,   // [256, 1]
    const float* __restrict__ W_hh,   // [256, 64]
    const float* __restrict__ b_ih,   // [256]
    const float* __restrict__ b_hh,   // [256]
    const float* __restrict__ fc1_w,  // [64, 64]
    const float* __restrict__ fc1_b,  // [64]
    const float* __restrict__ fc2_w,  // [10, 64]
    const float* __restrict__ fc2_b,  // [10]
    float* __restrict__ out)          // [B, 10]
{
    const int tid  = threadIdx.x;
    const int lane = tid & 63;
    const int w    = tid >> 6;        // wave id = gate (compute) = row (update)
    const int quad = lane >> 4;
    const int col  = lane & 15;
    const int row0 = blockIdx.x * ROWS;

    __shared__ short whi[32 * 512];          // 32 KB: W_hh hi fragments
    __shared__ short wlo[32 * 512];          // 32 KB: W_hh lo fragments
    // A-frag double buffer, swizzled rows (R10-verified):
    // phys(R) = R*8 + (R>>4)*8 shorts; hi at [0,1088), lo at [1088,2176).
    __shared__ short abuf[2][2176];
    __shared__ float gbuf[ROWS][HID][4];     // 4 KB: gates [m][u][g], 2-way banks
    __shared__ __align__(16) float xlds[ROWS][XCH + 4];
    __shared__ float hf[ROWS][HID + 1];
    __shared__ float r1buf[ROWS][HID + 1];

    // ---- setup: W_hh f32 -> bf16 hi/lo fragments in LDS (R5-verified layout)
    for (int idx = tid; idx < 256 * 64; idx += 256) {
        int r_ = idx >> 6;            // gate-major row 0..255
        int k  = idx & 63;
        float f = W_hh[r_ * 64 + k];
        unsigned short hi = f2bf(f);
        unsigned short lo = f2bf(f - bf2f(hi));
        int g = r_ >> 6, u = r_ & 63;
        int u4 = u >> 4, n = u & 15;
        int kt = k >> 5, kq = (k & 31) >> 3, j = k & 7;
        int off = (((u4 * 4 + g) * 2 + kt) * 64 + (kq * 16 + n)) * 8 + j;
        whi[off] = (short)hi;
        wlo[off] = (short)lo;
    }
    // zero BOTH A buffers (rows 4..15 never written -> stay zero)
    for (int idx = tid; idx < 2 * 2176; idx += 256) ((short*)abuf)[idx] = 0;
    __syncthreads();

    // ---- compute-phase constants: wave w = gate g, all 4 unit tiles ----
    const int g = w;
    bf16x8 Bhi[4][2], Blo[4][2];
    f32x4 biasC[4];
    f32x4 zerov = {0.f, 0.f, 0.f, 0.f};
    #pragma unroll
    for (int tt = 0; tt < 4; ++tt) {
        int t_ = tt * 4 + g;
        #pragma unroll
        for (int kt = 0; kt < 2; ++kt) {
            int off = ((t_ * 2 + kt) * 64 + lane) * 8;
            Bhi[tt][kt] = *(const bf16x8*)&whi[off];
            Blo[tt][kt] = *(const bf16x8*)&wlo[off];
            asm volatile("" : "+v"(Bhi[tt][kt]));
            asm volatile("" : "+v"(Blo[tt][kt]));
        }
        int u = tt * 16 + col;
        float bs = b_ih[g * HID + u] + b_hh[g * HID + u];
        #pragma unroll
        for (int r = 0; r < 4; ++r) biasC[tt][r] = bs;
    }

    // ---- update-phase constants: cell (row m = w, unit = lane) ----
    float wih_u[4];
    #pragma unroll
    for (int gg = 0; gg < 4; ++gg) wih_u[gg] = W_ih[gg * HID + lane];
    float cc = 0.f, hl = 0.f;

    // invariant LDS coords
    const int ard0 = lane * 8 + (lane >> 4) * 8;   // A-read (kt=1 at +544)
    // h-writer swizzled slot for cell (m=w, k=lane):
    //   s = (k>>5)*4 + ((k>>3)&3); R = s*16 + m; off = R*8 + s*8 + (k&7)
    const int s_w = (lane >> 5) * 4 + ((lane >> 3) & 3);
    const int awr = (s_w * 16 + w) * 8 + s_w * 8 + (lane & 7);

    const float* xbase = x + (size_t)row0 * T_STEPS;

    auto step = [&](auto cur_c, int tl) __attribute__((always_inline)) {
        constexpr int CUR = decltype(cur_c)::value;
        constexpr int NXT = CUR ^ 1;

        // ---- compute phase: gate w over all 64 units ----
        bf16x8 Ahi0 = *(const bf16x8*)&abuf[CUR][ard0];
        bf16x8 Ahi1 = *(const bf16x8*)&abuf[CUR][ard0 + 544];
        bf16x8 Alo0 = *(const bf16x8*)&abuf[CUR][1088 + ard0];
        bf16x8 Alo1 = *(const bf16x8*)&abuf[CUR][1088 + ard0 + 544];

        f32x4 accA[4], accB[4];
        #pragma unroll
        for (int tt = 0; tt < 4; ++tt) {
            accA[tt] = __builtin_amdgcn_mfma_f32_16x16x32_bf16(Ahi0, Bhi[tt][0], biasC[tt], 0, 0, 0);
            accB[tt] = __builtin_amdgcn_mfma_f32_16x16x32_bf16(Ahi1, Bhi[tt][1], zerov, 0, 0, 0);
        }
        #pragma unroll
        for (int tt = 0; tt < 4; ++tt) {
            accA[tt] = __builtin_amdgcn_mfma_f32_16x16x32_bf16(Alo0, Bhi[tt][0], accA[tt], 0, 0, 0);
            accB[tt] = __builtin_amdgcn_mfma_f32_16x16x32_bf16(Alo1, Bhi[tt][1], accB[tt], 0, 0, 0);
        }
        #pragma unroll
        for (int tt = 0; tt < 4; ++tt) {
            accA[tt] = __builtin_amdgcn_mfma_f32_16x16x32_bf16(Ahi0, Blo[tt][0], accA[tt], 0, 0, 0);
            accB[tt] = __builtin_amdgcn_mfma_f32_16x16x32_bf16(Ahi1, Blo[tt][1], accB[tt], 0, 0, 0);
        }

        // valid rows m = quad*4+r with m<4 -> quad==0 (16 active lanes).
        // gbuf[m][u][g]: bank=(u*4+g)%32, cols c,c+8 share bank -> 2-way, free.
        if (quad == 0) {
            #pragma unroll
            for (int tt = 0; tt < 4; ++tt) {
                int u = tt * 16 + col;
                #pragma unroll
                for (int r = 0; r < 4; ++r) {
                    gbuf[r][u][g] = accA[tt][r] + accB[tt][r];
                }
            }
        }
        __syncthreads();   // gates visible

        // ---- update phase: 1 cell/thread (row w, unit lane) ----
        f32x4 gv = *(const f32x4*)&gbuf[w][lane][0];  // i,f,g,o (bias included)
        float xv = xlds[w][tl];                        // wave-uniform broadcast

        float a0 = fmaf(xv, wih_u[0], gv[0]);
        float a1 = fmaf(xv, wih_u[1], gv[1]);
        float a2 = fmaf(xv, wih_u[2], gv[2]);
        float a3 = fmaf(xv, wih_u[3], gv[3]);
        float ig = sigm(a0);
        float fg = sigm(a1);
        float gg = tanh_f(a2);
        float og = sigm(a3);
        cc = fmaf(fg, cc, ig * gg);
        float h = og * tanh_f(cc);
        hl = h;

        unsigned short hh  = f2bf(h);
        unsigned short hlo = f2bf(h - bf2f(hh));
        abuf[NXT][awr]        = (short)hh;
        abuf[NXT][1088 + awr] = (short)hlo;

        __syncthreads();   // new h-frags visible
    };

    #pragma unroll 1
    for (int tc = 0; tc < T_STEPS; tc += 2) {
        const int tl = tc & (XCH - 1);
        if (tl == 0) {
            // refill x chunk (prev barrier => old chunk fully consumed)
            if (tid < 64) {
                int xr = tid >> 4, tb = (tid & 15) * 8;
                const float* src = xbase + (size_t)xr * T_STEPS + tc + tb;
                float4 v0 = *(const float4*)(src);
                float4 v1 = *(const float4*)(src + 4);
                *(float4*)&xlds[xr][tb]     = v0;
                *(float4*)&xlds[xr][tb + 4] = v1;
            }
            __syncthreads();
        }
        step(std::integral_constant<int, 0>{}, tl);      // reads abuf[0], writes abuf[1]
        step(std::integral_constant<int, 1>{}, tl + 1);  // reads abuf[1], writes abuf[0]
    }

    // ---- epilogue: fc1 (relu) + fc2 ----
    hf[w][lane] = hl;
    __syncthreads();

    {
        // thread -> (row m_ = w, unit = lane)
        float s = fc1_b[lane];
        const float4* wrow = (const float4*)(fc1_w + lane * HID);
        #pragma unroll
        for (int j4 = 0; j4 < HID / 4; ++j4) {
            float4 wv = wrow[j4];
            s = fmaf(hf[w][j4 * 4 + 0], wv.x, s);
            s = fmaf(hf[w][j4 * 4 + 1], wv.y, s);
            s = fmaf(hf[w][j4 * 4 + 2], wv.z, s);
            s = fmaf(hf[w][j4 * 4 + 3], wv.w, s);
        }
        r1buf[w][lane] = fmaxf(s, 0.0f);
    }
    __syncthreads();

    if (tid < ROWS * NCLS) {
        int m = tid / NCLS, cls = tid % NCLS;
        float s = fc2_b[cls];
        const float* w2 = fc2_w + cls * HID;
        #pragma unroll
        for (int j = 0; j < HID; ++j) s = fmaf(r1buf[m][j], w2[j], s);
        out[(size_t)(row0 + m) * NCLS + cls] = s;
    }
}

extern "C" void kernel_launch(void* const* d_in, const int* in_sizes, int n_in,
                              void* d_out, int out_size, void* d_ws, size_t ws_size,
                              hipStream_t stream) {
    const float* x     = (const float*)d_in[0];
    const float* W_ih  = (const float*)d_in[1];
    const float* W_hh  = (const float*)d_in[2];
    const float* b_ih  = (const float*)d_in[3];
    const float* b_hh  = (const float*)d_in[4];
    const float* fc1_w = (const float*)d_in[5];
    const float* fc1_b = (const float*)d_in[6];
    const float* fc2_w = (const float*)d_in[7];
    const float* fc2_b = (const float*)d_in[8];
    float* out = (float*)d_out;

    dim3 grid(256);   // 1024 rows / 4 rows per block -> one block per CU
    dim3 block(256);  // 4 waves
    lstm_mfma_kernel<<<grid, block, 0, stream>>>(x, W_ih, W_hh, b_ih, b_hh,
                                                 fc1_w, fc1_b, fc2_w, fc2_b, out);
}

// Round 12
// 1257.680 us; speedup vs baseline: 1.1101x; 1.0053x over previous
//
#include <hip/hip_runtime.h>
#include <type_traits>

// LSTMNet: B=1024, T=2048, H=64, NC=10, input_size=1.
// MFMA (16x16x32 bf16) split-bf16 (hi+lo) fp32 emulation.
// R12: TWO independent blocks per CU (fill each other's stalls).
//   R11 was latency-bound: 1 block/CU, 1 wave/SIMD -> 40% of step = exposed
//   barrier/LDS/trans latency. Fix: 512 blocks x 2 rows, LDS UNION so the
//   64KB W-staging area (dead after B-frags -> registers) is reused for the
//   runtime buffers -> 64.5KB/block -> 2 blocks/CU co-resident.
//   Per step: compute = all 4 waves (wave g = gate g, 4 unit-tiles, 24 MFMA);
//   update = waves 0-1 (row = w, unit = lane, 1 cell/thread).
//   R10/R11-verified swizzled abuf + unit-major gbuf layouts kept.

#define T_STEPS 2048
#define HID 64
#define NCLS 10
#define XCH 128   // x chunk length (steps)
#define ROWS 2    // batch rows per block

typedef short bf16x8 __attribute__((ext_vector_type(8)));
typedef float f32x4 __attribute__((ext_vector_type(4)));

__device__ __forceinline__ float sigm(float x) {
    float e = __builtin_amdgcn_exp2f(-1.4426950408889634f * x);
    return __builtin_amdgcn_rcpf(1.0f + e);
}
__device__ __forceinline__ float tanh_f(float x) {
    float e = __builtin_amdgcn_exp2f(-2.8853900817779268f * x);
    return fmaf(2.0f, __builtin_amdgcn_rcpf(1.0f + e), -1.0f);
}
__device__ __forceinline__ unsigned short f2bf(float f) {  // RNE f32->bf16
    unsigned u = __builtin_bit_cast(unsigned, f);
    u = u + 0x7FFFu + ((u >> 16) & 1u);
    return (unsigned short)(u >> 16);
}
__device__ __forceinline__ float bf2f(unsigned short s) {
    return __builtin_bit_cast(float, ((unsigned)s) << 16);
}

__global__ __attribute__((amdgpu_flat_work_group_size(256, 256),
                          amdgpu_waves_per_eu(2, 2)))
void lstm_mfma_kernel(
    const float* __restrict__ x,      // [B, 1, T]
    const float* __restrict__ W_ih,   // [256, 1]
    const float* __restrict__ W_hh,   // [256, 64]
    const float* __restrict__ b_ih,   // [256]
    const float* __restrict__ b_hh,   // [256]
    const float* __restrict__ fc1_w,  // [64, 64]
    const float* __restrict__ fc1_b,  // [64]
    const float* __restrict__ fc2_w,  // [10, 64]
    const float* __restrict__ fc2_b,  // [10]
    float* __restrict__ out)          // [B, 10]
{
    const int tid  = threadIdx.x;
    const int lane = tid & 63;
    const int w    = tid >> 6;        // wave id = gate (compute) = row (update, w<2)
    const int quad = lane >> 4;
    const int col  = lane & 15;
    const int row0 = blockIdx.x * ROWS;

    // ---- LDS union: staging (64KB, dead after B-frag load) overlaps runtime ----
    __shared__ __align__(16) char smem[65536];
    short* whi = (short*)smem;                 // staging [0,32768)
    short* wlo = (short*)(smem + 32768);       // staging [32768,65536)
    // runtime (valid only after the staging->register handoff sync):
    short (*abuf)[2176]        = (short(*)[2176])smem;              //  8704 B
    float (*gbuf)[HID][4]      = (float(*)[HID][4])(smem + 8704);   //  2048 B
    float (*xlds)[XCH + 4]     = (float(*)[XCH + 4])(smem + 10752); //  1056 B
    float (*hf)[HID + 1]       = (float(*)[HID + 1])(smem + 11808); //   520 B
    float (*r1buf)[HID + 1]    = (float(*)[HID + 1])(smem + 12328); //   520 B

    // ---- stage: W_hh f32 -> bf16 hi/lo fragments (R5-verified layout) ----
    for (int idx = tid; idx < 256 * 64; idx += 256) {
        int r_ = idx >> 6;            // gate-major row 0..255
        int k  = idx & 63;
        float f = W_hh[r_ * 64 + k];
        unsigned short hi = f2bf(f);
        unsigned short lo = f2bf(f - bf2f(hi));
        int g = r_ >> 6, u = r_ & 63;
        int u4 = u >> 4, n = u & 15;
        int kt = k >> 5, kq = (k & 31) >> 3, j = k & 7;
        int off = (((u4 * 4 + g) * 2 + kt) * 64 + (kq * 16 + n)) * 8 + j;
        whi[off] = (short)hi;
        wlo[off] = (short)lo;
    }
    __syncthreads();

    // ---- B fragments -> registers (wave w = gate g) ----
    const int g = w;
    bf16x8 Bhi[4][2], Blo[4][2];
    f32x4 biasC[4];
    f32x4 zerov = {0.f, 0.f, 0.f, 0.f};
    #pragma unroll
    for (int tt = 0; tt < 4; ++tt) {
        int t_ = tt * 4 + g;
        #pragma unroll
        for (int kt = 0; kt < 2; ++kt) {
            int off = ((t_ * 2 + kt) * 64 + lane) * 8;
            Bhi[tt][kt] = *(const bf16x8*)&whi[off];
            Blo[tt][kt] = *(const bf16x8*)&wlo[off];
            asm volatile("" : "+v"(Bhi[tt][kt]));
            asm volatile("" : "+v"(Blo[tt][kt]));
        }
        int u = tt * 16 + col;
        float bs = b_ih[g * HID + u] + b_hh[g * HID + u];
        #pragma unroll
        for (int r = 0; r < 4; ++r) biasC[tt][r] = bs;
    }
    __syncthreads();   // all waves done READING staging; smem may be reused now

    // zero BOTH A buffers (rows 2..15 never written -> stay zero = h0)
    for (int idx = tid; idx < 2 * 2176; idx += 256) ((short*)abuf)[idx] = 0;

    // ---- update-phase constants: cell (row m = w, unit = lane), w < 2 ----
    float wih_u[4];
    #pragma unroll
    for (int gg = 0; gg < 4; ++gg) wih_u[gg] = W_ih[gg * HID + lane];
    float cc = 0.f, hl = 0.f;

    // invariant LDS coords
    const int ard0 = lane * 8 + (lane >> 4) * 8;   // A-read (kt=1 at +544)
    const int s_w  = (lane >> 5) * 4 + ((lane >> 3) & 3);
    const int awr  = (s_w * 16 + w) * 8 + s_w * 8 + (lane & 7);  // h-write (m=w)

    const float* xbase = x + (size_t)row0 * T_STEPS;
    __syncthreads();   // abuf zeroed

    auto step = [&](auto cur_c, int tl) __attribute__((always_inline)) {
        constexpr int CUR = decltype(cur_c)::value;
        constexpr int NXT = CUR ^ 1;

        // ---- compute phase: gate w over all 64 units ----
        bf16x8 Ahi0 = *(const bf16x8*)&abuf[CUR][ard0];
        bf16x8 Ahi1 = *(const bf16x8*)&abuf[CUR][ard0 + 544];
        bf16x8 Alo0 = *(const bf16x8*)&abuf[CUR][1088 + ard0];
        bf16x8 Alo1 = *(const bf16x8*)&abuf[CUR][1088 + ard0 + 544];

        f32x4 accA[4], accB[4];
        #pragma unroll
        for (int tt = 0; tt < 4; ++tt) {
            accA[tt] = __builtin_amdgcn_mfma_f32_16x16x32_bf16(Ahi0, Bhi[tt][0], biasC[tt], 0, 0, 0);
            accB[tt] = __builtin_amdgcn_mfma_f32_16x16x32_bf16(Ahi1, Bhi[tt][1], zerov, 0, 0, 0);
        }
        #pragma unroll
        for (int tt = 0; tt < 4; ++tt) {
            accA[tt] = __builtin_amdgcn_mfma_f32_16x16x32_bf16(Alo0, Bhi[tt][0], accA[tt], 0, 0, 0);
            accB[tt] = __builtin_amdgcn_mfma_f32_16x16x32_bf16(Alo1, Bhi[tt][1], accB[tt], 0, 0, 0);
        }
        #pragma unroll
        for (int tt = 0; tt < 4; ++tt) {
            accA[tt] = __builtin_amdgcn_mfma_f32_16x16x32_bf16(Ahi0, Blo[tt][0], accA[tt], 0, 0, 0);
            accB[tt] = __builtin_amdgcn_mfma_f32_16x16x32_bf16(Ahi1, Blo[tt][1], accB[tt], 0, 0, 0);
        }

        // valid rows m = quad*4+r < 2 -> quad==0, r in {0,1}
        if (quad == 0) {
            #pragma unroll
            for (int tt = 0; tt < 4; ++tt) {
                int u = tt * 16 + col;
                gbuf[0][u][g] = accA[tt][0] + accB[tt][0];
                gbuf[1][u][g] = accA[tt][1] + accB[tt][1];
            }
        }
        __syncthreads();   // gates visible

        if (w < ROWS) {
            // ---- update phase: 1 cell/thread (row w, unit lane) ----
            f32x4 gv = *(const f32x4*)&gbuf[w][lane][0];
            float xv = xlds[w][tl];   // wave-uniform broadcast

            float a0 = fmaf(xv, wih_u[0], gv[0]);
            float a1 = fmaf(xv, wih_u[1], gv[1]);
            float a2 = fmaf(xv, wih_u[2], gv[2]);
            float a3 = fmaf(xv, wih_u[3], gv[3]);
            float ig = sigm(a0);
            float fg = sigm(a1);
            float gg = tanh_f(a2);
            float og = sigm(a3);
            cc = fmaf(fg, cc, ig * gg);
            float h = og * tanh_f(cc);
            hl = h;

            unsigned short hh  = f2bf(h);
            unsigned short hlo = f2bf(h - bf2f(hh));
            abuf[NXT][awr]        = (short)hh;
            abuf[NXT][1088 + awr] = (short)hlo;
        }
        __syncthreads();   // new h-frags visible
    };

    #pragma unroll 1
    for (int tc = 0; tc < T_STEPS; tc += 2) {
        const int tl = tc & (XCH - 1);
        if (tl == 0) {
            // refill x chunk (prev barrier => old chunk fully consumed)
            if (tid < 16 * ROWS) {
                int xr = tid >> 4, tb = (tid & 15) * 8;
                const float* src = xbase + (size_t)xr * T_STEPS + tc + tb;
                float4 v0 = *(const float4*)(src);
                float4 v1 = *(const float4*)(src + 4);
                *(float4*)&xlds[xr][tb]     = v0;
                *(float4*)&xlds[xr][tb + 4] = v1;
            }
            __syncthreads();
        }
        step(std::integral_constant<int, 0>{}, tl);      // reads abuf[0], writes abuf[1]
        step(std::integral_constant<int, 1>{}, tl + 1);  // reads abuf[1], writes abuf[0]
    }

    // ---- epilogue: fc1 (relu) + fc2 ----
    if (w < ROWS) hf[w][lane] = hl;
    __syncthreads();

    if (w < ROWS) {
        // thread -> (row = w, unit = lane)
        float s = fc1_b[lane];
        const float4* wrow = (const float4*)(fc1_w + lane * HID);
        #pragma unroll
        for (int j4 = 0; j4 < HID / 4; ++j4) {
            float4 wv = wrow[j4];
            s = fmaf(hf[w][j4 * 4 + 0], wv.x, s);
            s = fmaf(hf[w][j4 * 4 + 1], wv.y, s);
            s = fmaf(hf[w][j4 * 4 + 2], wv.z, s);
            s = fmaf(hf[w][j4 * 4 + 3], wv.w, s);
        }
        r1buf[w][lane] = fmaxf(s, 0.0f);
    }
    __syncthreads();

    if (tid < ROWS * NCLS) {
        int m = tid / NCLS, cls = tid % NCLS;
        float s = fc2_b[cls];
        const float* w2 = fc2_w + cls * HID;
        #pragma unroll
        for (int j = 0; j < HID; ++j) s = fmaf(r1buf[m][j], w2[j], s);
        out[(size_t)(row0 + m) * NCLS + cls] = s;
    }
}

extern "C" void kernel_launch(void* const* d_in, const int* in_sizes, int n_in,
                              void* d_out, int out_size, void* d_ws, size_t ws_size,
                              hipStream_t stream) {
    const float* x     = (const float*)d_in[0];
    const float* W_ih  = (const float*)d_in[1];
    const float* W_hh  = (const float*)d_in[2];
    const float* b_ih  = (const float*)d_in[3];
    const float* b_hh  = (const float*)d_in[4];
    const float* fc1_w = (const float*)d_in[5];
    const float* fc1_b = (const float*)d_in[6];
    const float* fc2_w = (const float*)d_in[7];
    const float* fc2_b = (const float*)d_in[8];
    float* out = (float*)d_out;

    dim3 grid(512);   // 1024 rows / 2 rows per block -> 2 blocks per CU
    dim3 block(256);  // 4 waves
    lstm_mfma_kernel<<<grid, block, 0, stream>>>(x, W_ih, W_hh, b_ih, b_hh,
                                                 fc1_w, fc1_b, fc2_w, fc2_b, out);
}

// Round 13
// 1065.125 us; speedup vs baseline: 1.3108x; 1.1808x over previous
//
#include <hip/hip_runtime.h>
#include <type_traits>

// LSTMNet: B=1024, T=2048, H=64, NC=10, input_size=1.
// MFMA (16x16x32 bf16), 2-PASS split: W exact (Whi+Wlo), h quantized to
// single bf16. R12 post-mortem: MFMA pipe was the floor (52% MfmaUtil;
// 2 blocks x 24 MFMA x ~19.4cyc = 930 of 1474 cyc/SIMD/step). 3->2 passes
// cuts that to 621 and halves the abuf traffic (A-reads 4->2, h-writes 2->1).
// Precision: dropped term is W*(h-hhi) — mean-zero h-rounding noise (2^-9),
// damped by forget-gate feedback; predicted final absmax ~5e-4 < 3.1e-3.
// Structure (R12-verified): 512 blocks x 256 thr (4 waves), 2 rows/block,
// 2 blocks/CU via the 64KB-staging LDS union; per step every wave computes
// its gate (16 MFMAs), waves 0-1 update 1 cell/thread; 2 barriers/step;
// swizzled abuf + unit-major gbuf (R10/R11-verified layouts).

#define T_STEPS 2048
#define HID 64
#define NCLS 10
#define XCH 128   // x chunk length (steps)
#define ROWS 2    // batch rows per block

typedef short bf16x8 __attribute__((ext_vector_type(8)));
typedef float f32x4 __attribute__((ext_vector_type(4)));

__device__ __forceinline__ float sigm(float x) {
    float e = __builtin_amdgcn_exp2f(-1.4426950408889634f * x);
    return __builtin_amdgcn_rcpf(1.0f + e);
}
__device__ __forceinline__ float tanh_f(float x) {
    float e = __builtin_amdgcn_exp2f(-2.8853900817779268f * x);
    return fmaf(2.0f, __builtin_amdgcn_rcpf(1.0f + e), -1.0f);
}
__device__ __forceinline__ unsigned short f2bf(float f) {  // RNE f32->bf16
    unsigned u = __builtin_bit_cast(unsigned, f);
    u = u + 0x7FFFu + ((u >> 16) & 1u);
    return (unsigned short)(u >> 16);
}
__device__ __forceinline__ float bf2f(unsigned short s) {
    return __builtin_bit_cast(float, ((unsigned)s) << 16);
}

__global__ __attribute__((amdgpu_flat_work_group_size(256, 256),
                          amdgpu_waves_per_eu(2, 2)))
void lstm_mfma_kernel(
    const float* __restrict__ x,      // [B, 1, T]
    const float* __restrict__ W_ih,   // [256, 1]
    const float* __restrict__ W_hh,   // [256, 64]
    const float* __restrict__ b_ih,   // [256]
    const float* __restrict__ b_hh,   // [256]
    const float* __restrict__ fc1_w,  // [64, 64]
    const float* __restrict__ fc1_b,  // [64]
    const float* __restrict__ fc2_w,  // [10, 64]
    const float* __restrict__ fc2_b,  // [10]
    float* __restrict__ out)          // [B, 10]
{
    const int tid  = threadIdx.x;
    const int lane = tid & 63;
    const int w    = tid >> 6;        // wave id = gate (compute) = row (update, w<2)
    const int quad = lane >> 4;
    const int col  = lane & 15;
    const int row0 = blockIdx.x * ROWS;

    // ---- LDS union: staging (64KB, dead after B-frag load) overlaps runtime ----
    __shared__ __align__(16) char smem[65536];
    short* whi = (short*)smem;                 // staging [0,32768)
    short* wlo = (short*)(smem + 32768);       // staging [32768,65536)
    // runtime (valid only after the staging->register handoff sync):
    // abuf: hi-only now; per buffer 1088 shorts (swizzled rows, 2176 B)
    short (*abuf)[1088]        = (short(*)[1088])smem;              // 4352 B
    float (*gbuf)[HID][4]      = (float(*)[HID][4])(smem + 4352);   // 2048 B
    float (*xlds)[XCH + 4]     = (float(*)[XCH + 4])(smem + 6400);  // 1056 B
    float (*hf)[HID + 1]       = (float(*)[HID + 1])(smem + 7456);  //  520 B
    float (*r1buf)[HID + 1]    = (float(*)[HID + 1])(smem + 7976);  //  520 B

    // ---- stage: W_hh f32 -> bf16 hi/lo fragments (R5-verified layout) ----
    for (int idx = tid; idx < 256 * 64; idx += 256) {
        int r_ = idx >> 6;            // gate-major row 0..255
        int k  = idx & 63;
        float f = W_hh[r_ * 64 + k];
        unsigned short hi = f2bf(f);
        unsigned short lo = f2bf(f - bf2f(hi));
        int g = r_ >> 6, u = r_ & 63;
        int u4 = u >> 4, n = u & 15;
        int kt = k >> 5, kq = (k & 31) >> 3, j = k & 7;
        int off = (((u4 * 4 + g) * 2 + kt) * 64 + (kq * 16 + n)) * 8 + j;
        whi[off] = (short)hi;
        wlo[off] = (short)lo;
    }
    __syncthreads();

    // ---- B fragments -> registers (wave w = gate g) ----
    const int g = w;
    bf16x8 Bhi[4][2], Blo[4][2];
    f32x4 biasC[4];
    f32x4 zerov = {0.f, 0.f, 0.f, 0.f};
    #pragma unroll
    for (int tt = 0; tt < 4; ++tt) {
        int t_ = tt * 4 + g;
        #pragma unroll
        for (int kt = 0; kt < 2; ++kt) {
            int off = ((t_ * 2 + kt) * 64 + lane) * 8;
            Bhi[tt][kt] = *(const bf16x8*)&whi[off];
            Blo[tt][kt] = *(const bf16x8*)&wlo[off];
            asm volatile("" : "+v"(Bhi[tt][kt]));
            asm volatile("" : "+v"(Blo[tt][kt]));
        }
        int u = tt * 16 + col;
        float bs = b_ih[g * HID + u] + b_hh[g * HID + u];
        #pragma unroll
        for (int r = 0; r < 4; ++r) biasC[tt][r] = bs;
    }
    __syncthreads();   // all waves done READING staging; smem may be reused now

    // zero BOTH A buffers (rows 2..15 never written -> stay zero = h0)
    for (int idx = tid; idx < 2 * 1088; idx += 256) ((short*)abuf)[idx] = 0;

    // ---- update-phase constants: cell (row m = w, unit = lane), w < 2 ----
    float wih_u[4];
    #pragma unroll
    for (int gg = 0; gg < 4; ++gg) wih_u[gg] = W_ih[gg * HID + lane];
    float cc = 0.f, hl = 0.f;

    // invariant LDS coords
    const int ard0 = lane * 8 + (lane >> 4) * 8;   // A-read (kt=1 at +544)
    const int s_w  = (lane >> 5) * 4 + ((lane >> 3) & 3);
    const int awr  = (s_w * 16 + w) * 8 + s_w * 8 + (lane & 7);  // h-write (m=w)

    const float* xbase = x + (size_t)row0 * T_STEPS;
    __syncthreads();   // abuf zeroed

    auto step = [&](auto cur_c, int tl) __attribute__((always_inline)) {
        constexpr int CUR = decltype(cur_c)::value;
        constexpr int NXT = CUR ^ 1;

        // ---- compute phase: gate w over all 64 units, 2-pass (16 MFMA) ----
        bf16x8 Ahi0 = *(const bf16x8*)&abuf[CUR][ard0];
        bf16x8 Ahi1 = *(const bf16x8*)&abuf[CUR][ard0 + 544];

        f32x4 accA[4], accB[4];
        #pragma unroll
        for (int tt = 0; tt < 4; ++tt) {
            accA[tt] = __builtin_amdgcn_mfma_f32_16x16x32_bf16(Ahi0, Bhi[tt][0], biasC[tt], 0, 0, 0);
            accB[tt] = __builtin_amdgcn_mfma_f32_16x16x32_bf16(Ahi1, Bhi[tt][1], zerov, 0, 0, 0);
        }
        #pragma unroll
        for (int tt = 0; tt < 4; ++tt) {
            accA[tt] = __builtin_amdgcn_mfma_f32_16x16x32_bf16(Ahi0, Blo[tt][0], accA[tt], 0, 0, 0);
            accB[tt] = __builtin_amdgcn_mfma_f32_16x16x32_bf16(Ahi1, Blo[tt][1], accB[tt], 0, 0, 0);
        }

        // valid rows m = quad*4+r < 2 -> quad==0, r in {0,1}
        if (quad == 0) {
            #pragma unroll
            for (int tt = 0; tt < 4; ++tt) {
                int u = tt * 16 + col;
                gbuf[0][u][g] = accA[tt][0] + accB[tt][0];
                gbuf[1][u][g] = accA[tt][1] + accB[tt][1];
            }
        }
        __syncthreads();   // gates visible

        if (w < ROWS) {
            // ---- update phase: 1 cell/thread (row w, unit lane) ----
            f32x4 gv = *(const f32x4*)&gbuf[w][lane][0];
            float xv = xlds[w][tl];   // wave-uniform broadcast

            float a0 = fmaf(xv, wih_u[0], gv[0]);
            float a1 = fmaf(xv, wih_u[1], gv[1]);
            float a2 = fmaf(xv, wih_u[2], gv[2]);
            float a3 = fmaf(xv, wih_u[3], gv[3]);
            float ig = sigm(a0);
            float fg = sigm(a1);
            float gg = tanh_f(a2);
            float og = sigm(a3);
            cc = fmaf(fg, cc, ig * gg);
            float h = og * tanh_f(cc);
            hl = h;

            abuf[NXT][awr] = (short)f2bf(h);
        }
        __syncthreads();   // new h-frags visible
    };

    #pragma unroll 1
    for (int tc = 0; tc < T_STEPS; tc += 2) {
        const int tl = tc & (XCH - 1);
        if (tl == 0) {
            // refill x chunk (prev barrier => old chunk fully consumed)
            if (tid < 16 * ROWS) {
                int xr = tid >> 4, tb = (tid & 15) * 8;
                const float* src = xbase + (size_t)xr * T_STEPS + tc + tb;
                float4 v0 = *(const float4*)(src);
                float4 v1 = *(const float4*)(src + 4);
                *(float4*)&xlds[xr][tb]     = v0;
                *(float4*)&xlds[xr][tb + 4] = v1;
            }
            __syncthreads();
        }
        step(std::integral_constant<int, 0>{}, tl);      // reads abuf[0], writes abuf[1]
        step(std::integral_constant<int, 1>{}, tl + 1);  // reads abuf[1], writes abuf[0]
    }

    // ---- epilogue: fc1 (relu) + fc2 ----
    if (w < ROWS) hf[w][lane] = hl;
    __syncthreads();

    if (w < ROWS) {
        // thread -> (row = w, unit = lane)
        float s = fc1_b[lane];
        const float4* wrow = (const float4*)(fc1_w + lane * HID);
        #pragma unroll
        for (int j4 = 0; j4 < HID / 4; ++j4) {
            float4 wv = wrow[j4];
            s = fmaf(hf[w][j4 * 4 + 0], wv.x, s);
            s = fmaf(hf[w][j4 * 4 + 1], wv.y, s);
            s = fmaf(hf[w][j4 * 4 + 2], wv.z, s);
            s = fmaf(hf[w][j4 * 4 + 3], wv.w, s);
        }
        r1buf[w][lane] = fmaxf(s, 0.0f);
    }
    __syncthreads();

    if (tid < ROWS * NCLS) {
        int m = tid / NCLS, cls = tid % NCLS;
        float s = fc2_b[cls];
        const float* w2 = fc2_w + cls * HID;
        #pragma unroll
        for (int j = 0; j < HID; ++j) s = fmaf(r1buf[m][j], w2[j], s);
        out[(size_t)(row0 + m) * NCLS + cls] = s;
    }
}

extern "C" void kernel_launch(void* const* d_in, const int* in_sizes, int n_in,
                              void* d_out, int out_size, void* d_ws, size_t ws_size,
                              hipStream_t stream) {
    const float* x     = (const float*)d_in[0];
    const float* W_ih  = (const float*)d_in[1];
    const float* W_hh  = (const float*)d_in[2];
    const float* b_ih  = (const float*)d_in[3];
    const float* b_hh  = (const float*)d_in[4];
    const float* fc1_w = (const float*)d_in[5];
    const float* fc1_b = (const float*)d_in[6];
    const float* fc2_w = (const float*)d_in[7];
    const float* fc2_b = (const float*)d_in[8];
    float* out = (float*)d_out;

    dim3 grid(512);   // 1024 rows / 2 rows per block -> 2 blocks per CU
    dim3 block(256);  // 4 waves
    lstm_mfma_kernel<<<grid, block, 0, stream>>>(x, W_ih, W_hh, b_ih, b_hh,
                                                 fc1_w, fc1_b, fc2_w, fc2_b, out);
}

// Round 14
// 852.578 us; speedup vs baseline: 1.6376x; 1.2493x over previous
//
#include <hip/hip_runtime.h>
#include <type_traits>

// LSTMNet: B=1024, T=2048, H=64, NC=10, input_size=1.
// MFMA (16x16x32 bf16), SINGLE-pass: W and h both quantized to bf16.
// R13 post-mortem: model confirmed (MFMA pipe 621 of 1248 cyc/SIMD/step at
// 2-pass). R14 halves it again (8 MFMA/wave/step, kt-chained, depth 2,
// no merge adds) and fixes the designed-in 8-way gbuf read conflict
// (layout [m][4][HID] gate-planes: stride-1 reads/writes, 2-way = free).
// Precision: dropped residuals Wlo*h (+ Whi*hlo) ~3e-4/gate/step on top of
// measured 9.8e-4 -> predicted absmax 1.5-2.8e-3 < 3.1e-3 threshold (RISK;
// fallback = restore Wlo pass, keep gbuf fix).
// Structure (R12/R13-verified): 512 blocks x 256 thr (4 waves), 2 rows/block,
// 2 blocks/CU (LDS union, now 32KB staging); wave g computes gate g (4 unit
// tiles), waves 0-1 update 1 cell/thread; 2 barriers/step; swizzled abuf.

#define T_STEPS 2048
#define HID 64
#define NCLS 10
#define XCH 128   // x chunk length (steps)
#define ROWS 2    // batch rows per block

typedef short bf16x8 __attribute__((ext_vector_type(8)));
typedef float f32x4 __attribute__((ext_vector_type(4)));

__device__ __forceinline__ float sigm(float x) {
    float e = __builtin_amdgcn_exp2f(-1.4426950408889634f * x);
    return __builtin_amdgcn_rcpf(1.0f + e);
}
__device__ __forceinline__ float tanh_f(float x) {
    float e = __builtin_amdgcn_exp2f(-2.8853900817779268f * x);
    return fmaf(2.0f, __builtin_amdgcn_rcpf(1.0f + e), -1.0f);
}
__device__ __forceinline__ unsigned short f2bf(float f) {  // RNE f32->bf16
    unsigned u = __builtin_bit_cast(unsigned, f);
    u = u + 0x7FFFu + ((u >> 16) & 1u);
    return (unsigned short)(u >> 16);
}

__global__ __attribute__((amdgpu_flat_work_group_size(256, 256),
                          amdgpu_waves_per_eu(2, 2)))
void lstm_mfma_kernel(
    const float* __restrict__ x,      // [B, 1, T]
    const float* __restrict__ W_ih,   // [256, 1]
    const float* __restrict__ W_hh,   // [256, 64]
    const float* __restrict__ b_ih,   // [256]
    const float* __restrict__ b_hh,   // [256]
    const float* __restrict__ fc1_w,  // [64, 64]
    const float* __restrict__ fc1_b,  // [64]
    const float* __restrict__ fc2_w,  // [10, 64]
    const float* __restrict__ fc2_b,  // [10]
    float* __restrict__ out)          // [B, 10]
{
    const int tid  = threadIdx.x;
    const int lane = tid & 63;
    const int w    = tid >> 6;        // wave id = gate (compute) = row (update, w<2)
    const int quad = lane >> 4;
    const int col  = lane & 15;
    const int row0 = blockIdx.x * ROWS;

    // ---- LDS union: 32KB staging (dead after B-frag load) overlaps runtime ----
    __shared__ __align__(16) char smem[32768];
    short* whi = (short*)smem;                 // staging [0,32768)
    // runtime (valid only after the staging->register handoff sync):
    short (*abuf)[1088]        = (short(*)[1088])smem;              // 4352 B
    float (*gbuf)[4][HID]      = (float(*)[4][HID])(smem + 4352);   // 2048 B
    float (*xlds)[XCH + 4]     = (float(*)[XCH + 4])(smem + 6400);  // 1056 B
    float (*hf)[HID + 1]       = (float(*)[HID + 1])(smem + 7456);  //  520 B
    float (*r1buf)[HID + 1]    = (float(*)[HID + 1])(smem + 7976);  //  520 B

    // ---- stage: W_hh f32 -> bf16 fragments (R5-verified layout) ----
    for (int idx = tid; idx < 256 * 64; idx += 256) {
        int r_ = idx >> 6;            // gate-major row 0..255
        int k  = idx & 63;
        float f = W_hh[r_ * 64 + k];
        int g = r_ >> 6, u = r_ & 63;
        int u4 = u >> 4, n = u & 15;
        int kt = k >> 5, kq = (k & 31) >> 3, j = k & 7;
        int off = (((u4 * 4 + g) * 2 + kt) * 64 + (kq * 16 + n)) * 8 + j;
        whi[off] = (short)f2bf(f);
    }
    __syncthreads();

    // ---- B fragments -> registers (wave w = gate g) ----
    const int g = w;
    bf16x8 Bq[4][2];
    f32x4 biasC[4];
    f32x4 zerov = {0.f, 0.f, 0.f, 0.f};
    #pragma unroll
    for (int tt = 0; tt < 4; ++tt) {
        int t_ = tt * 4 + g;
        #pragma unroll
        for (int kt = 0; kt < 2; ++kt) {
            int off = ((t_ * 2 + kt) * 64 + lane) * 8;
            Bq[tt][kt] = *(const bf16x8*)&whi[off];
            asm volatile("" : "+v"(Bq[tt][kt]));
        }
        int u = tt * 16 + col;
        float bs = b_ih[g * HID + u] + b_hh[g * HID + u];
        #pragma unroll
        for (int r = 0; r < 4; ++r) biasC[tt][r] = bs;
    }
    __syncthreads();   // all waves done READING staging; smem may be reused now

    // zero BOTH A buffers (rows 2..15 never written -> stay zero = h0)
    for (int idx = tid; idx < 2 * 1088; idx += 256) ((short*)abuf)[idx] = 0;

    // ---- update-phase constants: cell (row m = w, unit = lane), w < 2 ----
    float wih_u[4];
    #pragma unroll
    for (int gg = 0; gg < 4; ++gg) wih_u[gg] = W_ih[gg * HID + lane];
    float cc = 0.f, hl = 0.f;

    // invariant LDS coords
    const int ard0 = lane * 8 + (lane >> 4) * 8;   // A-read (kt=1 at +544)
    const int s_w  = (lane >> 5) * 4 + ((lane >> 3) & 3);
    const int awr  = (s_w * 16 + w) * 8 + s_w * 8 + (lane & 7);  // h-write (m=w)

    const float* xbase = x + (size_t)row0 * T_STEPS;
    __syncthreads();   // abuf zeroed

    auto step = [&](auto cur_c, int tl) __attribute__((always_inline)) {
        constexpr int CUR = decltype(cur_c)::value;
        constexpr int NXT = CUR ^ 1;

        // ---- compute phase: gate w over all 64 units, single-pass (8 MFMA) ----
        bf16x8 Ahi0 = *(const bf16x8*)&abuf[CUR][ard0];
        bf16x8 Ahi1 = *(const bf16x8*)&abuf[CUR][ard0 + 544];

        f32x4 acc[4];
        #pragma unroll
        for (int tt = 0; tt < 4; ++tt) {
            acc[tt] = __builtin_amdgcn_mfma_f32_16x16x32_bf16(Ahi0, Bq[tt][0], biasC[tt], 0, 0, 0);
        }
        #pragma unroll
        for (int tt = 0; tt < 4; ++tt) {
            acc[tt] = __builtin_amdgcn_mfma_f32_16x16x32_bf16(Ahi1, Bq[tt][1], acc[tt], 0, 0, 0);
        }

        // valid rows m = quad*4+r < 2 -> quad==0, r in {0,1}
        // gbuf[m][g][u]: 16 consecutive dwords per tile -> conflict-free.
        if (quad == 0) {
            #pragma unroll
            for (int tt = 0; tt < 4; ++tt) {
                int u = tt * 16 + col;
                gbuf[0][g][u] = acc[tt][0];
                gbuf[1][g][u] = acc[tt][1];
            }
        }
        __syncthreads();   // gates visible

        if (w < ROWS) {
            // ---- update phase: 1 cell/thread (row w, unit lane) ----
            // 4 stride-1 b32 reads (2-way banks = free; R13's b128 was 8-way)
            float g0 = gbuf[w][0][lane];
            float g1 = gbuf[w][1][lane];
            float g2 = gbuf[w][2][lane];
            float g3 = gbuf[w][3][lane];
            float xv = xlds[w][tl];   // wave-uniform broadcast

            float a0 = fmaf(xv, wih_u[0], g0);
            float a1 = fmaf(xv, wih_u[1], g1);
            float a2 = fmaf(xv, wih_u[2], g2);
            float a3 = fmaf(xv, wih_u[3], g3);
            float ig = sigm(a0);
            float fg = sigm(a1);
            float gg = tanh_f(a2);
            float og = sigm(a3);
            cc = fmaf(fg, cc, ig * gg);
            float h = og * tanh_f(cc);
            hl = h;

            abuf[NXT][awr] = (short)f2bf(h);
        }
        __syncthreads();   // new h-frags visible
    };

    #pragma unroll 1
    for (int tc = 0; tc < T_STEPS; tc += 2) {
        const int tl = tc & (XCH - 1);
        if (tl == 0) {
            // refill x chunk (prev barrier => old chunk fully consumed)
            if (tid < 16 * ROWS) {
                int xr = tid >> 4, tb = (tid & 15) * 8;
                const float* src = xbase + (size_t)xr * T_STEPS + tc + tb;
                float4 v0 = *(const float4*)(src);
                float4 v1 = *(const float4*)(src + 4);
                *(float4*)&xlds[xr][tb]     = v0;
                *(float4*)&xlds[xr][tb + 4] = v1;
            }
            __syncthreads();
        }
        step(std::integral_constant<int, 0>{}, tl);      // reads abuf[0], writes abuf[1]
        step(std::integral_constant<int, 1>{}, tl + 1);  // reads abuf[1], writes abuf[0]
    }

    // ---- epilogue: fc1 (relu) + fc2 ----
    if (w < ROWS) hf[w][lane] = hl;
    __syncthreads();

    if (w < ROWS) {
        // thread -> (row = w, unit = lane)
        float s = fc1_b[lane];
        const float4* wrow = (const float4*)(fc1_w + lane * HID);
        #pragma unroll
        for (int j4 = 0; j4 < HID / 4; ++j4) {
            float4 wv = wrow[j4];
            s = fmaf(hf[w][j4 * 4 + 0], wv.x, s);
            s = fmaf(hf[w][j4 * 4 + 1], wv.y, s);
            s = fmaf(hf[w][j4 * 4 + 2], wv.z, s);
            s = fmaf(hf[w][j4 * 4 + 3], wv.w, s);
        }
        r1buf[w][lane] = fmaxf(s, 0.0f);
    }
    __syncthreads();

    if (tid < ROWS * NCLS) {
        int m = tid / NCLS, cls = tid % NCLS;
        float s = fc2_b[cls];
        const float* w2 = fc2_w + cls * HID;
        #pragma unroll
        for (int j = 0; j < HID; ++j) s = fmaf(r1buf[m][j], w2[j], s);
        out[(size_t)(row0 + m) * NCLS + cls] = s;
    }
}

extern "C" void kernel_launch(void* const* d_in, const int* in_sizes, int n_in,
                              void* d_out, int out_size, void* d_ws, size_t ws_size,
                              hipStream_t stream) {
    const float* x     = (const float*)d_in[0];
    const float* W_ih  = (const float*)d_in[1];
    const float* W_hh  = (const float*)d_in[2];
    const float* b_ih  = (const float*)d_in[3];
    const float* b_hh  = (const float*)d_in[4];
    const float* fc1_w = (const float*)d_in[5];
    const float* fc1_b = (const float*)d_in[6];
    const float* fc2_w = (const float*)d_in[7];
    const float* fc2_b = (const float*)d_in[8];
    float* out = (float*)d_out;

    dim3 grid(512);   // 1024 rows / 2 rows per block -> 2 blocks per CU
    dim3 block(256);  // 4 waves
    lstm_mfma_kernel<<<grid, block, 0, stream>>>(x, W_ih, W_hh, b_ih, b_hh,
                                                 fc1_w, fc1_b, fc2_w, fc2_b, out);
}